// Round 21
// baseline (52.112 us; speedup 1.0000x reference)
//
#include <hip/hip_runtime.h>
#include <cstddef>

#define NUM_TYPE 64
#define DD 256
#define NN 8192
#define PSTR 264      // LDS row stride (bf16)

typedef __bf16 bf16x8 __attribute__((ext_vector_type(8)));
typedef __bf16 bf16x4 __attribute__((ext_vector_type(4)));
typedef float f32x4 __attribute__((ext_vector_type(4)));

__device__ __forceinline__ bf16x4 cvt4(float4 v) {
  bf16x4 h;
  h[0] = (__bf16)v.x; h[1] = (__bf16)v.y; h[2] = (__bf16)v.z; h[3] = (__bf16)v.w;
  return h;
}

__device__ __forceinline__ float tanh_fast(float x) {
  float xc = fminf(fmaxf(x, -15.f), 15.f);
  float e = __expf(2.f * xc);
  return (e - 1.f) / (e + 1.f);
}

// --- Single fused kernel -------------------------------------------------
// 256 blocks = (type t = bid>>2) x (col-block cb = bid&3), 1024 threads.
// Phase 1: per-block stable compaction of {i : bi[i]==t} -> rlist (LDS).
// Phase 2: stage L(t) and W panels (fp32 -> bf16) to LDS once.
// Phase 3: per 64-row group: stage A, 8x{3 ds_read + 2 MFMA}, epilogue.
// No workspace, no inter-block deps, one dispatch.
__global__ __launch_bounds__(1024, 1) void fused_all(
    const int* __restrict__ bi,
    const float* __restrict__ desc,
    const float* __restrict__ layer1,
    const float* __restrict__ W,
    const float* __restrict__ bias,
    float* __restrict__ out) {
  extern __shared__ char smem[];
  __bf16* At = (__bf16*)smem;                  // [64][PSTR]
  __bf16* Ll = At + 64 * PSTR;                 // [64][PSTR]
  __bf16* Wl = Ll + 64 * PSTR;                 // [64][PSTR]
  int* rlist = (int*)(Wl + 64 * PSTR);         // up to 8192 ints
  __shared__ int scanbuf[16];
  __shared__ int totcnt;

  const int bid = blockIdx.x;
  const int t = bid >> 2;
  const int cb = bid & 3;
  const int tid = threadIdx.x;
  const int lane = tid & 63;
  const int wid = tid >> 6;

  // ---- Phase 1: stable compaction (thread owns 8 consecutive elems) ----
  int flags = 0, c = 0;
  const int ebase = tid * 8;
#pragma unroll
  for (int k = 0; k < 8; ++k) {
    const int m = (bi[ebase + k] == t) ? 1 : 0;
    flags |= m << k;
    c += m;
  }
  int sc = c;                                  // wave-inclusive scan
#pragma unroll
  for (int d = 1; d < 64; d <<= 1) {
    const int o = __shfl_up(sc, d, 64);
    if (lane >= d) sc += o;
  }
  if (lane == 63) scanbuf[wid] = sc;
  __syncthreads();
  if (tid == 0) {
    int s = 0;
#pragma unroll
    for (int i = 0; i < 16; ++i) { const int v = scanbuf[i]; scanbuf[i] = s; s += v; }
    totcnt = s;
  }
  __syncthreads();
  int pos = scanbuf[wid] + sc - c;             // exclusive prefix
#pragma unroll
  for (int k = 0; k < 8; ++k)
    if (flags & (1 << k)) rlist[pos++] = ebase + k;
  const int cnt = totcnt;                      // broadcast via LDS
  __syncthreads();
  if (cnt == 0) return;

  // ---- Phase 2: stage L (fp32->bf16) and W (fp32->bf16) once ----
  {
    const float* Lsrc = layer1 + ((size_t)t * DD + cb * 64) * DD;
    const float* Wsrc = W + (size_t)(cb * 64) * DD;
#pragma unroll
    for (int it = 0; it < 4; ++it) {
      const int idx = it * 1024 + tid;         // 64 rows x 64 f4-segs
      const int col = idx >> 6, seg = idx & 63;
      *reinterpret_cast<bf16x4*>(Ll + col * PSTR + seg * 4) =
          cvt4(*reinterpret_cast<const float4*>(Lsrc + (size_t)col * DD + seg * 4));
      *reinterpret_cast<bf16x4*>(Wl + col * PSTR + seg * 4) =
          cvt4(*reinterpret_cast<const float4*>(Wsrc + (size_t)col * DD + seg * 4));
    }
  }

  const int l15 = lane & 15;
  const int lg = lane >> 4;
  const int wr = wid & 3;                      // row 16-group
  const int wc = wid >> 2;                     // col 16-group
  const int colg = cb * 64 + wc * 16 + l15;
  const float bv = bias[colg];
  const int ngr = (cnt + 63) >> 6;

  for (int j = 0; j < ngr; ++j) {
    const int first = j * 64;
    __syncthreads();                           // prev-iter LDS reads done
    // ---- stage A group: 64 rows x 64 f4-segs, 4/thread ----
#pragma unroll
    for (int it = 0; it < 4; ++it) {
      const int idx = it * 1024 + tid;
      const int row = idx >> 6, seg = idx & 63;
      const int rr = first + row;
      float4 v = make_float4(0.f, 0.f, 0.f, 0.f);
      if (rr < cnt) v = *reinterpret_cast<const float4*>(desc + (size_t)rlist[rr] * DD + seg * 4);
      *reinterpret_cast<bf16x4*>(At + row * PSTR + seg * 4) = cvt4(v);
    }
    __syncthreads();                           // A (and L/W on j=0) visible

    f32x4 accL = {0.f, 0.f, 0.f, 0.f};
    f32x4 accW = {0.f, 0.f, 0.f, 0.f};
#pragma unroll
    for (int kc = 0; kc < 8; ++kc) {
      bf16x8 af = *reinterpret_cast<const bf16x8*>(At + (wr * 16 + l15) * PSTR + kc * 32 + lg * 8);
      bf16x8 bl = *reinterpret_cast<const bf16x8*>(Ll + (wc * 16 + l15) * PSTR + kc * 32 + lg * 8);
      bf16x8 bw = *reinterpret_cast<const bf16x8*>(Wl + (wc * 16 + l15) * PSTR + kc * 32 + lg * 8);
      accL = __builtin_amdgcn_mfma_f32_16x16x32_bf16(af, bl, accL, 0, 0, 0);
      accW = __builtin_amdgcn_mfma_f32_16x16x32_bf16(af, bw, accW, 0, 0, 0);
    }

    // epilogue: acc row = lg*4+i, col = l15
    const int orow = first + wr * 16 + l15;
    const int sOut = (orow < cnt) ? rlist[orow] : -1;
#pragma unroll
    for (int i = 0; i < 4; ++i) {
      const int sv = __shfl(sOut, lg * 4 + i, 64);
      if (sv >= 0)
        __builtin_nontemporal_store(tanh_fast(accL[i]) + accW[i] + bv,
                                    out + (size_t)sv * DD + colg);
    }
  }
}

extern "C" void kernel_launch(void* const* d_in, const int* in_sizes, int n_in,
                              void* d_out, int out_size, void* d_ws, size_t ws_size,
                              hipStream_t stream) {
  const int* bi       = (const int*)d_in[0];
  const float* desc   = (const float*)d_in[1];
  const float* layer1 = (const float*)d_in[2];
  const float* W      = (const float*)d_in[3];
  const float* bias   = (const float*)d_in[4];
  float* out = (float*)d_out;

  const int ldsBytes = 3 * 64 * PSTR * 2 + NN * 4;   // 101376 + 32768 = 134144 B

  hipLaunchKernelGGL(fused_all, dim3(256), dim3(1024), ldsBytes, stream,
                     bi, desc, layer1, W, bias, out);
}

// Round 22
// 25.650 us; speedup vs baseline: 2.0317x; 2.0317x over previous
//
#include <hip/hip_runtime.h>
#include <cstddef>

#define NUM_TYPE 64
#define DD 256
#define NN 8192
#define GM64 192
#define PSTR 264      // LDS row stride in bf16 (512B data + 16B pad): banks 2-way free

typedef __bf16 bf16x8 __attribute__((ext_vector_type(8)));
typedef __bf16 bf16x4 __attribute__((ext_vector_type(4)));
typedef float f32x4 __attribute__((ext_vector_type(4)));

__device__ __forceinline__ bf16x4 cvt4(float4 v) {
  bf16x4 h;
  h[0] = (__bf16)v.x; h[1] = (__bf16)v.y; h[2] = (__bf16)v.z; h[3] = (__bf16)v.w;
  return h;
}

__device__ __forceinline__ float tanh_fast(float x) {
  float xc = fminf(fmaxf(x, -15.f), 15.f);
  float e = __expf(2.f * xc);
  return (e - 1.f) / (e + 1.f);
}

// --- Kernel 1 (proven): block 0 = perm/type_off; blocks 1..264 convert ---
// desc (524288 f4) + W (16384 f4) -> bf16; 264 x 2048 = 540672 f4.
__global__ __launch_bounds__(1024) void perm_conv(
    const int* __restrict__ bi,
    const float* __restrict__ desc,
    const float* __restrict__ W,
    int* __restrict__ type_off, int* __restrict__ perm,
    __bf16* __restrict__ descB, __bf16* __restrict__ Wb) {
  const int b = blockIdx.x;
  const int tid = threadIdx.x;
  if (b == 0) {
    __shared__ int wcnt[16][NUM_TYPE];
    __shared__ int wbase[16][NUM_TYPE];
    __shared__ int cnt[NUM_TYPE];
    __shared__ int tstart[NUM_TYPE];
    __shared__ int totals[1];
    const int w = tid >> 6;
    for (int i = tid; i < 16 * NUM_TYPE; i += 1024) ((int*)wcnt)[i] = 0;
    __syncthreads();
    int myv[8];
#pragma unroll
    for (int rnd = 0; rnd < 8; ++rnd) {
      int v = bi[rnd * 1024 + tid];
      myv[rnd] = v;
      atomicAdd(&wcnt[w][v], 1);
    }
    __syncthreads();
    if (tid < NUM_TYPE) {
      int s = 0;
#pragma unroll
      for (int ww = 0; ww < 16; ++ww) { wbase[ww][tid] = s; s += wcnt[ww][tid]; }
      cnt[tid] = s;
    }
    __syncthreads();
    if (tid == 0) {
      int s = 0;
      for (int t = 0; t < NUM_TYPE; ++t) { tstart[t] = s; s += cnt[t]; }
      totals[0] = s;
    }
    __syncthreads();
    if (tid < NUM_TYPE) {
      const int s0 = tstart[tid];
      type_off[tid] = s0;
#pragma unroll
      for (int ww = 0; ww < 16; ++ww) wbase[ww][tid] += s0;
    }
    if (tid == 0) type_off[NUM_TYPE] = totals[0];
    __syncthreads();
#pragma unroll
    for (int rnd = 0; rnd < 8; ++rnd) {
      int v = myv[rnd];
      int p = atomicAdd(&wbase[w][v], 1);
      perm[p] = rnd * 1024 + tid;
    }
  } else {
    const float4* srcD = reinterpret_cast<const float4*>(desc);
    const float4* srcW = reinterpret_cast<const float4*>(W);
#pragma unroll
    for (int it = 0; it < 2; ++it) {
      const int idx = (b - 1) * 2048 + it * 1024 + tid;
      if (idx < 524288)
        *reinterpret_cast<bf16x4*>(descB + (size_t)idx * 4) = cvt4(srcD[idx]);
      else
        *reinterpret_cast<bf16x4*>(Wb + (size_t)(idx - 524288) * 4) = cvt4(srcW[idx - 524288]);
    }
  }
}

// --- Kernel 2: resident-panel GEMM, N=32, 2 blocks/CU --------------------
// 512 blocks: t = (d&7) + 8*((d>>3)&7), cb = d>>6  (all 8 cb of a type on
// one XCD -> shared descB rows are L2-local). 512 threads / 8 waves.
// L (fp32->bf16, 32 cols) + W (bf16, 32 cols) staged ONCE; loop over the
// type's 64-row A groups staging A only. Wave = 16x16 tile: wr=wid>>1 rows,
// wc=wid&1 cols.
__global__ __launch_bounds__(512, 2) void gemm_res32(
    const __bf16* __restrict__ descB,
    const float* __restrict__ layer1,
    const __bf16* __restrict__ Wb,
    const float* __restrict__ bias,
    const int* __restrict__ type_off,
    const int* __restrict__ perm,
    float* __restrict__ out) {
  extern __shared__ __bf16 lds[];
  __bf16* At = lds;                      // [64][PSTR]
  __bf16* Ll = lds + 64 * PSTR;          // [32][PSTR]
  __bf16* Wl = lds + 96 * PSTR;          // [32][PSTR]

  const int d = blockIdx.x;
  const int t = (d & 7) + 8 * ((d >> 3) & 7);
  const int cb = d >> 6;                 // 0..7
  const int off = type_off[t];
  const int limit = type_off[t + 1];
  const int cnt = limit - off;
  if (cnt <= 0) return;
  const int ngr = (cnt + 63) >> 6;

  const int tid = threadIdx.x;
  const int wid = tid >> 6;
  const int lane = tid & 63;
  const int l15 = lane & 15;
  const int lg = lane >> 4;
  const int wr = wid >> 1;               // 0..3: row 16-group
  const int wc = wid & 1;                // 0..1: col 16-group

  // ---- stage L (fp32->bf16) and W (bf16) once ----
  {
    const float* Lsrc = layer1 + ((size_t)t * DD + cb * 32) * DD;
#pragma unroll
    for (int it = 0; it < 4; ++it) {
      const int idx = it * 512 + tid;    // 0..2047: 32 cols x 64 f4-segs
      const int col = idx >> 6, seg = idx & 63;
      *reinterpret_cast<bf16x4*>(Ll + col * PSTR + seg * 4) =
          cvt4(*reinterpret_cast<const float4*>(Lsrc + (size_t)col * DD + seg * 4));
    }
    const __bf16* Wsrc = Wb + (size_t)(cb * 32) * DD;
#pragma unroll
    for (int it = 0; it < 2; ++it) {
      const int idx = it * 512 + tid;    // 0..1023: 32 cols x 32 bf16x8
      const int col = idx >> 5, seg = idx & 31;
      *reinterpret_cast<bf16x8*>(Wl + col * PSTR + seg * 8) =
          *reinterpret_cast<const bf16x8*>(Wsrc + (size_t)col * DD + seg * 8);
    }
  }

  const int colg = cb * 32 + wc * 16 + l15;
  const float bv = bias[colg];

  for (int j = 0; j < ngr; ++j) {
    const int first = off + j * 64;
    if (j > 0) __syncthreads();          // prior-group LDS reads done
    // ---- stage A group: 64 rows x 32 bf16x8, 4/thread ----
#pragma unroll
    for (int it = 0; it < 4; ++it) {
      const int idx = it * 512 + tid;
      const int row = idx >> 5, seg = idx & 31;
      const int rr = first + row;
      bf16x8 v = {};
      if (rr < limit) v = *reinterpret_cast<const bf16x8*>(descB + (size_t)perm[rr] * DD + seg * 8);
      *reinterpret_cast<bf16x8*>(At + row * PSTR + seg * 8) = v;
    }
    __syncthreads();                     // A (and L/W on j=0) visible

    f32x4 accL = {0.f, 0.f, 0.f, 0.f};
    f32x4 accW = {0.f, 0.f, 0.f, 0.f};
#pragma unroll
    for (int kc = 0; kc < 8; ++kc) {
      bf16x8 af = *reinterpret_cast<const bf16x8*>(At + (wr * 16 + l15) * PSTR + kc * 32 + lg * 8);
      bf16x8 bl = *reinterpret_cast<const bf16x8*>(Ll + (wc * 16 + l15) * PSTR + kc * 32 + lg * 8);
      bf16x8 bw = *reinterpret_cast<const bf16x8*>(Wl + (wc * 16 + l15) * PSTR + kc * 32 + lg * 8);
      accL = __builtin_amdgcn_mfma_f32_16x16x32_bf16(af, bl, accL, 0, 0, 0);
      accW = __builtin_amdgcn_mfma_f32_16x16x32_bf16(af, bw, accW, 0, 0, 0);
    }

    // epilogue: acc row = lg*4+i, col = l15 (proven layout)
    const int orow = first + wr * 16 + l15;
    const int sOut = (orow < limit) ? perm[orow] : -1;
#pragma unroll
    for (int i = 0; i < 4; ++i) {
      const int sv = __shfl(sOut, lg * 4 + i, 64);
      if (sv >= 0)
        __builtin_nontemporal_store(tanh_fast(accL[i]) + accW[i] + bv,
                                    out + (size_t)sv * DD + colg);
    }
  }
}

extern "C" void kernel_launch(void* const* d_in, const int* in_sizes, int n_in,
                              void* d_out, int out_size, void* d_ws, size_t ws_size,
                              hipStream_t stream) {
  const int* bi       = (const int*)d_in[0];
  const float* desc   = (const float*)d_in[1];
  const float* layer1 = (const float*)d_in[2];
  const float* W      = (const float*)d_in[3];
  const float* bias   = (const float*)d_in[4];
  float* out = (float*)d_out;

  char* ws = (char*)d_ws;
  int* type_off = (int*)(ws);                      // 65 ints   @ 0
  int* perm     = (int*)(ws + 8192);               // 8192 ints @ 8 KB
  __bf16* descB = (__bf16*)(ws + 65536);           // 4 MB
  __bf16* Wb    = (__bf16*)(ws + 65536 + 4194304); // 128 KB

  const int ldsBytes = 128 * PSTR * 2;             // 67,584 B -> 2 blocks/CU

  hipLaunchKernelGGL(perm_conv, dim3(265), dim3(1024), 0, stream,
                     bi, desc, W, type_off, perm, descB, Wb);
  hipLaunchKernelGGL(gemm_res32, dim3(512), dim3(512), ldsBytes, stream,
                     descB, layer1, Wb, bias, type_off, perm, out);
}